// Round 8
// baseline (1451.629 us; speedup 1.0000x reference)
//
#include <hip/hip_runtime.h>
#include <math.h>

#define N_NODES 50000
#define N_EDGES 1600000
#define C 64
#define OUTC 7

#define NB 196         // coarse buckets: dst >> 8  (49999>>8 = 195)
#define BCAP 10240     // bucket capacity (mean 8192, sigma ~90)
#define CHUNK 8192     // edges per phase-1 workgroup

#define ZROW N_NODES   // zero-row index in tables (OOB slots add +0.0)
#define NPB 32         // nodes per gather block
#define LSTRIDE 65     // LDS accum row stride in f32 (odd -> conflict-free)
#define L7S 11         // LDS stride for 7-ch accum (odd)

typedef __attribute__((ext_vector_type(8))) short bf16x8;   // 8 bf16 = 4 VGPR
typedef __attribute__((ext_vector_type(4))) float f32x4;    // MFMA acc

// fp32 -> bf16 (RNE), packed pair into u32 (lo = even channel, hi = odd)
__device__ __forceinline__ unsigned int pk_bf16(float a, float b) {
    unsigned int ua = __float_as_uint(a);
    ua = (ua + 0x7FFFu + ((ua >> 16) & 1u)) >> 16;
    unsigned int ub = __float_as_uint(b);
    ub = (ub + 0x7FFFu + ((ub >> 16) & 1u)) >> 16;
    return ua | (ub << 16);
}

union U4B8 { uint4 u; bf16x8 s; };

// ---------------- prep: pack W1+W2 to bf16, zero gcursor ----------------
__global__ __launch_bounds__(256) void prep(const float* __restrict__ W1,
                                            const float* __restrict__ W2,
                                            unsigned int* __restrict__ Wb1,
                                            unsigned int* __restrict__ Wb2,
                                            int* __restrict__ gcursor) {
    const int b = blockIdx.x;
    const int tid = threadIdx.x;
    if (b < 8) {
        int idx = b * 256 + tid;
        float2 v = ((const float2*)W1)[idx];
        Wb1[idx] = pk_bf16(v.x, v.y);
    } else if (b < 16) {
        int idx = (b - 8) * 256 + tid;
        float2 v = ((const float2*)W2)[idx];
        Wb2[idx] = pk_bf16(v.x, v.y);
    } else {
        if (tid < NB) gcursor[tid] = 0;
    }
}

// ---------------- CSR build, phase 1: coarse binning ----------------
__global__ __launch_bounds__(256) void bin_kernel(const int* __restrict__ src,
                                                  const int* __restrict__ dst,
                                                  unsigned int* __restrict__ buckets,
                                                  int* __restrict__ gcursor) {
    __shared__ unsigned int staged[CHUNK];          // 32 KB
    __shared__ int hist[NB], scanb[NB], cur[NB], baseb[NB];
    const int tid = threadIdx.x;
    const int base = blockIdx.x * CHUNK;
    int n = N_EDGES - base; if (n > CHUNK) n = CHUNK;

    for (int b = tid; b < NB; b += 256) { hist[b] = 0; cur[b] = 0; }
    __syncthreads();

    const int4* src4 = (const int4*)(src + base);
    const int4* dst4 = (const int4*)(dst + base);
    unsigned int v[32];
    int nv = n >> 2;
#pragma unroll
    for (int k = 0; k < 8; ++k) {
        int i4 = k * 256 + tid;
        if (i4 < nv) {
            int4 s4 = src4[i4];
            int4 d4 = dst4[i4];
            unsigned int d0 = (unsigned int)d4.x, d1 = (unsigned int)d4.y;
            unsigned int d2 = (unsigned int)d4.z, d3 = (unsigned int)d4.w;
            v[k * 4 + 0] = (d0 << 16) | (unsigned int)s4.x;
            v[k * 4 + 1] = (d1 << 16) | (unsigned int)s4.y;
            v[k * 4 + 2] = (d2 << 16) | (unsigned int)s4.z;
            v[k * 4 + 3] = (d3 << 16) | (unsigned int)s4.w;
            atomicAdd(&hist[d0 >> 8], 1);
            atomicAdd(&hist[d1 >> 8], 1);
            atomicAdd(&hist[d2 >> 8], 1);
            atomicAdd(&hist[d3 >> 8], 1);
        }
    }
    __syncthreads();
    if (tid == 0) {
        int run = 0;
        for (int b = 0; b < NB; ++b) { scanb[b] = run; run += hist[b]; }
    }
    __syncthreads();
#pragma unroll
    for (int k = 0; k < 8; ++k) {
        int i4 = k * 256 + tid;
        if (i4 < nv) {
#pragma unroll
            for (int q = 0; q < 4; ++q) {
                unsigned int w = v[k * 4 + q];
                int b = w >> 24;
                int p = scanb[b] + atomicAdd(&cur[b], 1);
                staged[p] = w;
            }
        }
    }
    __syncthreads();
    if (tid < NB) baseb[tid] = atomicAdd(&gcursor[tid], hist[tid]);
    __syncthreads();
    for (int i = tid; i < n; i += 256) {
        unsigned int w = staged[i];
        int b = w >> 24;
        buckets[(size_t)b * BCAP + baseb[b] + (i - scanb[b])] = w;
    }
}

// ---------------- CSR build, phase 2: per-bucket local CSR ----------------
// csr entry = (dst&255)<<16 | src  (dst_local for the LDS gathers).
__global__ __launch_bounds__(256) void build_csr(const unsigned int* __restrict__ buckets,
                                                 const int* __restrict__ gcursor,
                                                 unsigned int* __restrict__ csr,
                                                 int* __restrict__ off) {
    __shared__ int hist[256], part[256], offx[256], cur[256];
    __shared__ int gl[NB];
    __shared__ int s_cnt, s_base;
    const int tid = threadIdx.x;
    const int b = blockIdx.x;

    hist[tid] = 0;
    cur[tid] = 0;
    if (tid < NB) gl[tid] = gcursor[tid];
    __syncthreads();
    if (tid == 0) {
        int bs = 0;
        for (int i = 0; i < b; ++i) bs += gl[i];
        s_base = bs;
        s_cnt = gl[b];
    }
    __syncthreads();
    const int cnt = s_cnt;
    const int gbase = s_base;
    const unsigned int* bk = buckets + (size_t)b * BCAP;

    for (int i = tid; i < cnt; i += 256) {
        atomicAdd(&hist[(bk[i] >> 16) & 255], 1);
    }
    __syncthreads();
    part[tid] = hist[tid];
    __syncthreads();
    for (int d = 1; d < 256; d <<= 1) {
        int t = (tid >= d) ? part[tid - d] : 0;
        __syncthreads();
        part[tid] += t;
        __syncthreads();
    }
    offx[tid] = (tid == 0) ? 0 : part[tid - 1];
    __syncthreads();
    int node = b * 256 + tid;
    if (node < N_NODES) off[node] = gbase + offx[tid];
    if (b == NB - 1 && tid == 0) off[N_NODES] = gbase + cnt;
    for (int i = tid; i < cnt; i += 256) {
        unsigned int w = bk[i];
        int dl = (w >> 16) & 255;
        int p = offx[dl] + atomicAdd(&cur[dl], 1);
        csr[gbase + p] = ((unsigned int)dl << 16) | (w & 0xFFFFu);
    }
}

// ---------------- MFMA linears ----------------
// One wave = 16 rows x 64 cols via 8x mfma_f32_16x16x32_bf16.
// Block 0 zeroes t-table row ZROW (the gather zero-row).

// Layer 1: fp32 x in (A-frag packed in-register), bf16 t out.
__global__ __launch_bounds__(256) void linear64_mfma_x(const float* __restrict__ x,
                                                       const unsigned int* __restrict__ Wb,
                                                       unsigned int* __restrict__ out) {
    if (blockIdx.x == 0 && threadIdx.x < 32)
        out[(size_t)ZROW * 32 + threadIdx.x] = 0u;
    const int wave = threadIdx.x >> 6;
    const int lane = threadIdx.x & 63;
    const int quad = lane >> 4;
    const int l16  = lane & 15;
    const int rbase = blockIdx.x * 64 + wave * 16;
    if (rbase >= N_NODES) return;

    U4B8 bfrag[4][2];
#pragma unroll
    for (int ct = 0; ct < 4; ++ct)
#pragma unroll
        for (int kt = 0; kt < 2; ++kt)
            bfrag[ct][kt].u = *(const uint4*)(Wb + (ct * 16 + l16) * 32 + kt * 16 + quad * 4);

    U4B8 afrag[2];
#pragma unroll
    for (int kt = 0; kt < 2; ++kt) {
        const float4* xp = (const float4*)(x + (size_t)(rbase + l16) * 64 + kt * 32 + quad * 8);
        float4 f0 = xp[0];
        float4 f1 = xp[1];
        afrag[kt].u.x = pk_bf16(f0.x, f0.y);
        afrag[kt].u.y = pk_bf16(f0.z, f0.w);
        afrag[kt].u.z = pk_bf16(f1.x, f1.y);
        afrag[kt].u.w = pk_bf16(f1.z, f1.w);
    }

    f32x4 acc[4];
#pragma unroll
    for (int ct = 0; ct < 4; ++ct) {
        f32x4 z = {0.f, 0.f, 0.f, 0.f};
        z = __builtin_amdgcn_mfma_f32_16x16x32_bf16(afrag[0].s, bfrag[ct][0].s, z, 0, 0, 0);
        z = __builtin_amdgcn_mfma_f32_16x16x32_bf16(afrag[1].s, bfrag[ct][1].s, z, 0, 0, 0);
        acc[ct] = z;
    }

    const int colp = l16 >> 1;
    const bool even = (l16 & 1) == 0;
#pragma unroll
    for (int ct = 0; ct < 4; ++ct) {
#pragma unroll
        for (int i = 0; i < 4; ++i) {
            float v = acc[ct][i];
            float p = __shfl_xor(v, 1, 64);
            if (even) {
                int row = rbase + quad * 4 + i;
                out[(size_t)row * 32 + ct * 8 + colp] = pk_bf16(v, p);
            }
        }
    }
}

// Layer 2: bf16 table in, bf16 t out.
__global__ __launch_bounds__(256) void linear64_mfma(const unsigned int* __restrict__ in,
                                                     const unsigned int* __restrict__ Wb,
                                                     unsigned int* __restrict__ out) {
    if (blockIdx.x == 0 && threadIdx.x < 32)
        out[(size_t)ZROW * 32 + threadIdx.x] = 0u;
    const int wave = threadIdx.x >> 6;
    const int lane = threadIdx.x & 63;
    const int quad = lane >> 4;
    const int l16  = lane & 15;
    const int rbase = blockIdx.x * 64 + wave * 16;
    if (rbase >= N_NODES) return;

    U4B8 bfrag[4][2];
#pragma unroll
    for (int ct = 0; ct < 4; ++ct)
#pragma unroll
        for (int kt = 0; kt < 2; ++kt)
            bfrag[ct][kt].u = *(const uint4*)(Wb + (ct * 16 + l16) * 32 + kt * 16 + quad * 4);

    U4B8 afrag[2];
#pragma unroll
    for (int kt = 0; kt < 2; ++kt)
        afrag[kt].u = *(const uint4*)(in + (size_t)(rbase + l16) * 32 + kt * 16 + quad * 4);

    f32x4 acc[4];
#pragma unroll
    for (int ct = 0; ct < 4; ++ct) {
        f32x4 z = {0.f, 0.f, 0.f, 0.f};
        z = __builtin_amdgcn_mfma_f32_16x16x32_bf16(afrag[0].s, bfrag[ct][0].s, z, 0, 0, 0);
        z = __builtin_amdgcn_mfma_f32_16x16x32_bf16(afrag[1].s, bfrag[ct][1].s, z, 0, 0, 0);
        acc[ct] = z;
    }

    const int colp = l16 >> 1;
    const bool even = (l16 & 1) == 0;
#pragma unroll
    for (int ct = 0; ct < 4; ++ct) {
#pragma unroll
        for (int i = 0; i < 4; ++i) {
            float v = acc[ct][i];
            float p = __shfl_xor(v, 1, 64);
            if (even) {
                int row = rbase + quad * 4 + i;
                out[(size_t)row * 32 + ct * 8 + colp] = pk_bf16(v, p);
            }
        }
    }
}

// ---------------- LDS-accumulator gathers ----------------
// Block owns NPB=32 consecutive dst nodes and their CONTIGUOUS csr range.
// 32 lane-groups (8 lanes each) walk disjoint sub-ranges (spaced ~1 node
// apart -> different dst_local -> no same-address atomic pileups).
// Iterations are INDEPENDENT: csr load -> t-row load -> 8x ds_add_f32.
// LDS stride 65 (odd): bank = (dl + 8*ch8 + j) mod 32 covers all 32 banks,
// 2 lanes/bank (free, m136). OOB lanes -> ZROW zero-row, dl=0 (+0.0).
// csr over-read <=31 u32 past e1 lands in 'off' (readable).
__device__ __forceinline__ void gather_accum_lds(const int* __restrict__ off,
                                                 const unsigned int* __restrict__ csr,
                                                 const unsigned int* __restrict__ tb,
                                                 float* acc) {
    const int tid = threadIdx.x;
    const int blk = blockIdx.x;
    for (int i = tid; i < NPB * LSTRIDE; i += 256) acc[i] = 0.f;
    int nend = blk * NPB + NPB; if (nend > N_NODES) nend = N_NODES;
    const int e0 = off[blk * NPB];
    const int e1 = off[nend];
    __syncthreads();
    const int range = e1 - e0;
    const int nIter = (range + 31) >> 5;
    const int q = tid >> 3;          // 32 edge-groups
    const int ch8 = tid & 7;
    const uint4* t4 = (const uint4*)tb;
    const int base = e0 + q * nIter;
#pragma unroll 4
    for (int it = 0; it < nIter; ++it) {
        int i = base + it;
        unsigned int w = csr[i];
        bool ok = i < e1;
        unsigned int srcn = ok ? (w & 0xFFFFu) : (unsigned int)ZROW;
        int dl = ok ? (int)((w >> 16) & (NPB - 1)) : 0;
        uint4 v = t4[(size_t)srcn * 8 + ch8];
        float* ap = acc + dl * LSTRIDE + ch8 * 8;
        atomicAdd(ap + 0, __uint_as_float(v.x << 16));
        atomicAdd(ap + 1, __uint_as_float(v.x & 0xFFFF0000u));
        atomicAdd(ap + 2, __uint_as_float(v.y << 16));
        atomicAdd(ap + 3, __uint_as_float(v.y & 0xFFFF0000u));
        atomicAdd(ap + 4, __uint_as_float(v.z << 16));
        atomicAdd(ap + 5, __uint_as_float(v.z & 0xFFFF0000u));
        atomicAdd(ap + 6, __uint_as_float(v.w << 16));
        atomicAdd(ap + 7, __uint_as_float(v.w & 0xFFFF0000u));
    }
    __syncthreads();
}

// layer-1/2 gather: + bias + relu -> bf16 h table.
__global__ __launch_bounds__(256) void gather64_lds(const int* __restrict__ off,
                                                    const unsigned int* __restrict__ csr,
                                                    const unsigned int* __restrict__ tb,
                                                    const float* __restrict__ b,
                                                    unsigned int* __restrict__ hb) {
    __shared__ float acc[NPB * LSTRIDE];
    gather_accum_lds(off, csr, tb, acc);
    const int tid = threadIdx.x;
    const int nl = tid >> 3, c8 = tid & 7;     // 8 threads/node, 8 ch each
    int node = blockIdx.x * NPB + nl;
    if (node >= N_NODES) return;
    const float* ap = acc + nl * LSTRIDE + c8 * 8;
    const float4 b0 = ((const float4*)b)[c8 * 2];
    const float4 b1 = ((const float4*)b)[c8 * 2 + 1];
    float r0 = fmaxf(ap[0] + b0.x, 0.f);
    float r1 = fmaxf(ap[1] + b0.y, 0.f);
    float r2 = fmaxf(ap[2] + b0.z, 0.f);
    float r3 = fmaxf(ap[3] + b0.w, 0.f);
    float r4 = fmaxf(ap[4] + b1.x, 0.f);
    float r5 = fmaxf(ap[5] + b1.y, 0.f);
    float r6 = fmaxf(ap[6] + b1.z, 0.f);
    float r7 = fmaxf(ap[7] + b1.w, 0.f);
    uint4 w;
    w.x = pk_bf16(r0, r1);
    w.y = pk_bf16(r2, r3);
    w.z = pk_bf16(r4, r5);
    w.w = pk_bf16(r6, r7);
    ((uint4*)(hb + (size_t)node * 32))[c8] = w;
}

// layer-2 gather + bias + relu + FUSED W3 projection -> bf16 t3 (16 B rows).
// 8 threads/node (same wave): partial dots over 8 ch, shfl-sum over c8.
// Block 0 zeroes t3 row ZROW for gather7's OOB redirect.
__global__ __launch_bounds__(256) void gather64_lds_w3(const int* __restrict__ off,
                                                       const unsigned int* __restrict__ csr,
                                                       const unsigned int* __restrict__ tb,
                                                       const float* __restrict__ b,
                                                       const float* __restrict__ W3,
                                                       unsigned int* __restrict__ t3) {
    if (blockIdx.x == 0 && threadIdx.x < 4)
        t3[(size_t)ZROW * 4 + threadIdx.x] = 0u;
    __shared__ float acc[NPB * LSTRIDE];
    gather_accum_lds(off, csr, tb, acc);
    const int tid = threadIdx.x;
    const int nl = tid >> 3, c8 = tid & 7;
    int node = blockIdx.x * NPB + nl;
    if (node >= N_NODES) return;
    const float* ap = acc + nl * LSTRIDE + c8 * 8;
    const float4 b0 = ((const float4*)b)[c8 * 2];
    const float4 b1 = ((const float4*)b)[c8 * 2 + 1];
    float r[8];
    r[0] = fmaxf(ap[0] + b0.x, 0.f);
    r[1] = fmaxf(ap[1] + b0.y, 0.f);
    r[2] = fmaxf(ap[2] + b0.z, 0.f);
    r[3] = fmaxf(ap[3] + b0.w, 0.f);
    r[4] = fmaxf(ap[4] + b1.x, 0.f);
    r[5] = fmaxf(ap[5] + b1.y, 0.f);
    r[6] = fmaxf(ap[6] + b1.z, 0.f);
    r[7] = fmaxf(ap[7] + b1.w, 0.f);
    float p[7];
#pragma unroll
    for (int j = 0; j < 7; ++j) {
        const float4 wa = *(const float4*)(W3 + j * 64 + c8 * 8);
        const float4 wb = *(const float4*)(W3 + j * 64 + c8 * 8 + 4);
        float t = r[0] * wa.x + r[1] * wa.y + r[2] * wa.z + r[3] * wa.w
                + r[4] * wb.x + r[5] * wb.y + r[6] * wb.z + r[7] * wb.w;
        t += __shfl_xor(t, 1, 64);     // sum over the 8 c8 threads
        t += __shfl_xor(t, 2, 64);
        t += __shfl_xor(t, 4, 64);
        p[j] = t;
    }
    if (c8 == 0) {
        uint4 w;
        w.x = pk_bf16(p[0], p[1]);
        w.y = pk_bf16(p[2], p[3]);
        w.z = pk_bf16(p[4], p[5]);
        w.w = pk_bf16(p[6], 0.f);
        *(uint4*)(t3 + (size_t)node * 4) = w;
    }
}

// layer-3 gather: 1 edge/lane (uint4 t3 row), 7 ds_adds; + bias + lsm.
__global__ __launch_bounds__(256) void gather7_lds(const int* __restrict__ off,
                                                   const unsigned int* __restrict__ csr,
                                                   const unsigned int* __restrict__ t3,
                                                   const float* __restrict__ b,
                                                   float* __restrict__ out) {
    __shared__ float a7[NPB * L7S];
    const int tid = threadIdx.x;
    const int blk = blockIdx.x;
    for (int i = tid; i < NPB * L7S; i += 256) a7[i] = 0.f;
    int nend = blk * NPB + NPB; if (nend > N_NODES) nend = N_NODES;
    const int e0 = off[blk * NPB];
    const int e1 = off[nend];
    __syncthreads();
    const int range = e1 - e0;
    const int nIter = (range + 255) >> 8;     // 256 edges per block-iter
    const uint4* t4 = (const uint4*)t3;
    const int base = e0 + tid * nIter;
#pragma unroll 2
    for (int it = 0; it < nIter; ++it) {
        int i = base + it;
        unsigned int w = csr[i];
        bool ok = i < e1;
        unsigned int srcn = ok ? (w & 0xFFFFu) : (unsigned int)ZROW;
        int dl = ok ? (int)((w >> 16) & (NPB - 1)) : 0;
        uint4 v = t4[srcn];
        float* ap = a7 + dl * L7S;
        atomicAdd(ap + 0, __uint_as_float(v.x << 16));
        atomicAdd(ap + 1, __uint_as_float(v.x & 0xFFFF0000u));
        atomicAdd(ap + 2, __uint_as_float(v.y << 16));
        atomicAdd(ap + 3, __uint_as_float(v.y & 0xFFFF0000u));
        atomicAdd(ap + 4, __uint_as_float(v.z << 16));
        atomicAdd(ap + 5, __uint_as_float(v.z & 0xFFFF0000u));
        atomicAdd(ap + 6, __uint_as_float(v.w << 16));
    }
    __syncthreads();
    if (tid < NPB) {
        int node = blk * NPB + tid;
        if (node < N_NODES) {
            const float* ap = a7 + tid * L7S;
            float z0 = ap[0] + b[0];
            float z1 = ap[1] + b[1];
            float z2 = ap[2] + b[2];
            float z3 = ap[3] + b[3];
            float z4 = ap[4] + b[4];
            float z5 = ap[5] + b[5];
            float z6 = ap[6] + b[6];
            float m = fmaxf(fmaxf(fmaxf(z0, z1), fmaxf(z2, z3)),
                            fmaxf(fmaxf(z4, z5), z6));
            float ex = __expf(z0 - m) + __expf(z1 - m) + __expf(z2 - m)
                     + __expf(z3 - m) + __expf(z4 - m) + __expf(z5 - m)
                     + __expf(z6 - m);
            float l = m + __logf(ex);
            float* o = out + (size_t)node * 7;
            o[0] = z0 - l; o[1] = z1 - l; o[2] = z2 - l; o[3] = z3 - l;
            o[4] = z4 - l; o[5] = z5 - l; o[6] = z6 - l;
        }
    }
}

extern "C" void kernel_launch(void* const* d_in, const int* in_sizes, int n_in,
                              void* d_out, int out_size, void* d_ws, size_t ws_size,
                              hipStream_t stream) {
    const float* x  = (const float*)d_in[0];
    const int*   ei = (const int*)d_in[1];
    const float* W1 = (const float*)d_in[2];
    const float* b1 = (const float*)d_in[3];
    const float* W2 = (const float*)d_in[4];
    const float* b2 = (const float*)d_in[5];
    const float* W3 = (const float*)d_in[6];
    const float* b3 = (const float*)d_in[7];
    float* out = (float*)d_out;

    const int* src = ei;
    const int* dst = ei + N_EDGES;

    // workspace (round-3 layout):
    //   A (12.8 MB): buckets (8 MB, dead after build_csr) -> bf16 t table
    //                (6.4 MB + 128 B zero-row at ZROW)
    //   B (12.8 MB): Hbf (first 6.4 MB) -> t3 (dead Hbf reused; +ZROW row)
    //   then csr (6.4 MB; over-read lands in off), off, gcursor, Wb1/Wb2
    float* A = (float*)d_ws;
    float* B = A + (size_t)N_NODES * C;
    unsigned int* csr = (unsigned int*)(B + (size_t)N_NODES * C);
    int* off     = (int*)(csr + N_EDGES);          // 50001
    int* gcursor = off + N_NODES + 8;              // 196
    unsigned int* Wb1 = (unsigned int*)(gcursor + 256);   // 2048 u32
    unsigned int* Wb2 = Wb1 + 2048;                       // 2048 u32
    unsigned int* buckets = (unsigned int*)A;
    unsigned int* Abf     = (unsigned int*)A;      // bf16 t-table view
    unsigned int* Hbf     = (unsigned int*)B;      // bf16 h-table view
    unsigned int* T3      = (unsigned int*)B;      // t3 reuses Hbf (dead by then)

    const int mfmagrid = (N_NODES + 63) / 64;      // 782 blocks x 4 waves
    const int ggrid    = (N_NODES + NPB - 1) / NPB;  // 1563 blocks

    // ---- prep: pack W1/W2 + zero gcursor
    prep<<<17, 256, 0, stream>>>(W1, W2, Wb1, Wb2, gcursor);

    // ---- CSR build
    bin_kernel<<<(N_EDGES + CHUNK - 1) / CHUNK, 256, 0, stream>>>(src, dst, buckets, gcursor);
    build_csr<<<NB, 256, 0, stream>>>(buckets, gcursor, csr, off);

    // ---- layer 1 (Abf aliases buckets: must follow build_csr)
    linear64_mfma_x<<<mfmagrid, 256, 0, stream>>>(x, Wb1, Abf);
    gather64_lds<<<ggrid, 256, 0, stream>>>(off, csr, Abf, b1, Hbf);

    // ---- layer 2 linear
    linear64_mfma<<<mfmagrid, 256, 0, stream>>>(Hbf, Wb2, Abf);

    // ---- layer 2 gather + fused layer-3 linear (h2 never hits memory)
    gather64_lds_w3<<<ggrid, 256, 0, stream>>>(off, csr, Abf, b2, W3, T3);

    // ---- layer 3 aggregation + log_softmax
    gather7_lds<<<ggrid, 256, 0, stream>>>(off, csr, T3, b3, out);
}

// Round 9
// 215.929 us; speedup vs baseline: 6.7227x; 6.7227x over previous
//
#include <hip/hip_runtime.h>
#include <math.h>

#define N_NODES 50000
#define N_EDGES 1600000
#define C 64
#define OUTC 7

#define NB 196         // coarse buckets: dst >> 8  (49999>>8 = 195)
#define BCAP 10240     // bucket capacity (mean 8192, sigma ~90)
#define CHUNK 8192     // edges per phase-1 workgroup
#define BINBLKS 196    // (N_EDGES+CHUNK-1)/CHUNK

#define ZROW N_NODES   // zero-row index in tables (OOB slots add +0.0)

typedef __attribute__((ext_vector_type(8))) short bf16x8;   // 8 bf16 = 4 VGPR
typedef __attribute__((ext_vector_type(4))) float f32x4;    // MFMA acc
typedef __attribute__((ext_vector_type(2))) float f32x2;    // packed-math pair

// fp32 -> bf16 (RNE), packed pair into u32 (lo = even channel, hi = odd)
__device__ __forceinline__ unsigned int pk_bf16(float a, float b) {
    unsigned int ua = __float_as_uint(a);
    ua = (ua + 0x7FFFu + ((ua >> 16) & 1u)) >> 16;
    unsigned int ub = __float_as_uint(b);
    ub = (ub + 0x7FFFu + ((ub >> 16) & 1u)) >> 16;
    return ua | (ub << 16);
}

union U4B8 { uint4 u; bf16x8 s; };

// ---------------- prep: pack W1+W2 to bf16 (Wb1 used by lin1), zero gcursor --
__global__ __launch_bounds__(256) void prep(const float* __restrict__ W1,
                                            unsigned int* __restrict__ Wb1,
                                            int* __restrict__ gcursor) {
    const int b = blockIdx.x;
    const int tid = threadIdx.x;
    if (b < 8) {
        int idx = b * 256 + tid;
        float2 v = ((const float2*)W1)[idx];
        Wb1[idx] = pk_bf16(v.x, v.y);
    } else {
        if (tid < NB) gcursor[tid] = 0;
    }
}

// ---------------- fused: CSR phase-1 binning  +  layer-1 MFMA linear --------
// Blocks [0,BINBLKS): edge binning. Blocks [BINBLKS, BINBLKS+mfmagrid): lin1.
// Independent data: bin reads edge list / writes buckets+gcursor; lin1 reads
// x,Wb1 / writes t-table (region B). One dispatch -> lin1 hides under bin.
__global__ __launch_bounds__(256) void bin_lin1(const int* __restrict__ src,
                                                const int* __restrict__ dst,
                                                unsigned int* __restrict__ buckets,
                                                int* __restrict__ gcursor,
                                                const float* __restrict__ x,
                                                const unsigned int* __restrict__ Wb,
                                                unsigned int* __restrict__ tout) {
    __shared__ unsigned int staged[CHUNK];          // 32 KB (bin branch only)
    __shared__ int hist[NB], scanb[NB], cur[NB], baseb[NB];
    const int tid = threadIdx.x;

    if (blockIdx.x < BINBLKS) {
        const int bx = blockIdx.x;
        const int base = bx * CHUNK;
        int n = N_EDGES - base; if (n > CHUNK) n = CHUNK;

        for (int b = tid; b < NB; b += 256) { hist[b] = 0; cur[b] = 0; }
        __syncthreads();

        const int4* src4 = (const int4*)(src + base);
        const int4* dst4 = (const int4*)(dst + base);
        unsigned int v[32];
        int nv = n >> 2;
#pragma unroll
        for (int k = 0; k < 8; ++k) {
            int i4 = k * 256 + tid;
            if (i4 < nv) {
                int4 s4 = src4[i4];
                int4 d4 = dst4[i4];
                unsigned int d0 = (unsigned int)d4.x, d1 = (unsigned int)d4.y;
                unsigned int d2 = (unsigned int)d4.z, d3 = (unsigned int)d4.w;
                v[k * 4 + 0] = (d0 << 16) | (unsigned int)s4.x;
                v[k * 4 + 1] = (d1 << 16) | (unsigned int)s4.y;
                v[k * 4 + 2] = (d2 << 16) | (unsigned int)s4.z;
                v[k * 4 + 3] = (d3 << 16) | (unsigned int)s4.w;
                atomicAdd(&hist[d0 >> 8], 1);
                atomicAdd(&hist[d1 >> 8], 1);
                atomicAdd(&hist[d2 >> 8], 1);
                atomicAdd(&hist[d3 >> 8], 1);
            }
        }
        __syncthreads();
        if (tid == 0) {
            int run = 0;
            for (int b = 0; b < NB; ++b) { scanb[b] = run; run += hist[b]; }
        }
        __syncthreads();
#pragma unroll
        for (int k = 0; k < 8; ++k) {
            int i4 = k * 256 + tid;
            if (i4 < nv) {
#pragma unroll
                for (int q = 0; q < 4; ++q) {
                    unsigned int w = v[k * 4 + q];
                    int b = w >> 24;
                    int p = scanb[b] + atomicAdd(&cur[b], 1);
                    staged[p] = w;
                }
            }
        }
        __syncthreads();
        if (tid < NB) baseb[tid] = atomicAdd(&gcursor[tid], hist[tid]);
        __syncthreads();
        for (int i = tid; i < n; i += 256) {
            unsigned int w = staged[i];
            int b = w >> 24;
            buckets[(size_t)b * BCAP + baseb[b] + (i - scanb[b])] = w;
        }
        return;
    }

    // ---- lin1 branch: fp32 x -> bf16 t (MFMA), one wave = 16 rows.
    const int bx = blockIdx.x - BINBLKS;
    if (bx == 0 && tid < 32)
        tout[(size_t)ZROW * 32 + tid] = 0u;
    const int wave = tid >> 6;
    const int lane = tid & 63;
    const int quad = lane >> 4;
    const int l16  = lane & 15;
    const int rbase = bx * 64 + wave * 16;
    if (rbase >= N_NODES) return;

    U4B8 bfrag[4][2];
#pragma unroll
    for (int ct = 0; ct < 4; ++ct)
#pragma unroll
        for (int kt = 0; kt < 2; ++kt)
            bfrag[ct][kt].u = *(const uint4*)(Wb + (ct * 16 + l16) * 32 + kt * 16 + quad * 4);

    U4B8 afrag[2];
#pragma unroll
    for (int kt = 0; kt < 2; ++kt) {
        const float4* xp = (const float4*)(x + (size_t)(rbase + l16) * 64 + kt * 32 + quad * 8);
        float4 f0 = xp[0];
        float4 f1 = xp[1];
        afrag[kt].u.x = pk_bf16(f0.x, f0.y);
        afrag[kt].u.y = pk_bf16(f0.z, f0.w);
        afrag[kt].u.z = pk_bf16(f1.x, f1.y);
        afrag[kt].u.w = pk_bf16(f1.z, f1.w);
    }

    f32x4 acc[4];
#pragma unroll
    for (int ct = 0; ct < 4; ++ct) {
        f32x4 z = {0.f, 0.f, 0.f, 0.f};
        z = __builtin_amdgcn_mfma_f32_16x16x32_bf16(afrag[0].s, bfrag[ct][0].s, z, 0, 0, 0);
        z = __builtin_amdgcn_mfma_f32_16x16x32_bf16(afrag[1].s, bfrag[ct][1].s, z, 0, 0, 0);
        acc[ct] = z;
    }

    const int colp = l16 >> 1;
    const bool even = (l16 & 1) == 0;
#pragma unroll
    for (int ct = 0; ct < 4; ++ct) {
#pragma unroll
        for (int i = 0; i < 4; ++i) {
            float v = acc[ct][i];
            float p = __shfl_xor(v, 1, 64);
            if (even) {
                int row = rbase + quad * 4 + i;
                tout[(size_t)row * 32 + ct * 8 + colp] = pk_bf16(v, p);
            }
        }
    }
}

// ---------------- CSR build, phase 2: per-bucket local CSR ----------------
__global__ __launch_bounds__(256) void build_csr(const unsigned int* __restrict__ buckets,
                                                 const int* __restrict__ gcursor,
                                                 unsigned int* __restrict__ csr,
                                                 int* __restrict__ off) {
    __shared__ int hist[256], part[256], offx[256], cur[256];
    __shared__ int gl[NB];
    __shared__ int s_cnt, s_base;
    const int tid = threadIdx.x;
    const int b = blockIdx.x;

    hist[tid] = 0;
    cur[tid] = 0;
    if (tid < NB) gl[tid] = gcursor[tid];
    __syncthreads();
    if (tid == 0) {
        int bs = 0;
        for (int i = 0; i < b; ++i) bs += gl[i];
        s_base = bs;
        s_cnt = gl[b];
    }
    __syncthreads();
    const int cnt = s_cnt;
    const int gbase = s_base;
    const unsigned int* bk = buckets + (size_t)b * BCAP;

    for (int i = tid; i < cnt; i += 256) {
        atomicAdd(&hist[(bk[i] >> 16) & 255], 1);
    }
    __syncthreads();
    part[tid] = hist[tid];
    __syncthreads();
    for (int d = 1; d < 256; d <<= 1) {
        int t = (tid >= d) ? part[tid - d] : 0;
        __syncthreads();
        part[tid] += t;
        __syncthreads();
    }
    offx[tid] = (tid == 0) ? 0 : part[tid - 1];
    __syncthreads();
    int node = b * 256 + tid;
    if (node < N_NODES) off[node] = gbase + offx[tid];
    if (b == NB - 1 && tid == 0) off[N_NODES] = gbase + cnt;
    for (int i = tid; i < cnt; i += 256) {
        unsigned int w = bk[i];
        int dl = (w >> 16) & 255;
        int p = offx[dl] + atomicAdd(&cur[dl], 1);
        csr[gbase + p] = w & 0xFFFFu;
    }
}

// ---------------- gathers (round-3 proven loop) ----------------
#define ACC8(v)                                                              \
    do {                                                                     \
        s01 += (f32x2){__uint_as_float((v).x << 16),                         \
                       __uint_as_float((v).x & 0xFFFF0000u)};                \
        s23 += (f32x2){__uint_as_float((v).y << 16),                         \
                       __uint_as_float((v).y & 0xFFFF0000u)};                \
        s45 += (f32x2){__uint_as_float((v).z << 16),                         \
                       __uint_as_float((v).z & 0xFFFF0000u)};                \
        s67 += (f32x2){__uint_as_float((v).w << 16),                         \
                       __uint_as_float((v).w & 0xFFFF0000u)};                \
    } while (0)

// Layer-1 gather + bias b1 + relu + FUSED layer-2 linear (h1 @ W2^T, fp32)
// -> bf16 t2 table. After the d=8/16/32 reduce every lane holds h1 channels
// [8*ch8, 8*ch8+8); slot-group s computes t2 outputs [8s, 8s+8): 64 FMA/lane
// + xor-reduce over ch8 (d=1,2,4). h1 never touches memory; lin2 dispatch
// and the 12.8 MB h round trip are gone. Block 0 zeroes t2 row ZROW.
__global__ __launch_bounds__(256) void gather64_lin2(const int* __restrict__ off,
                                                     const unsigned int* __restrict__ csr_src,
                                                     const unsigned int* __restrict__ tb,
                                                     const float* __restrict__ b,
                                                     const float* __restrict__ W2,
                                                     unsigned int* __restrict__ t2) {
    if (blockIdx.x == 0 && threadIdx.x < 32)
        t2[(size_t)ZROW * 32 + threadIdx.x] = 0u;
    int node = blockIdx.x * 4 + (threadIdx.x >> 6);
    if (node >= N_NODES) return;
    const int lane = threadIdx.x & 63;
    const int slot = lane >> 3;
    const int ch8  = lane & 7;
    int e0 = off[node], e1 = off[node + 1];
    const uint4* t4 = (const uint4*)tb;
    f32x2 s01 = {0.f, 0.f}, s23 = {0.f, 0.f}, s45 = {0.f, 0.f}, s67 = {0.f, 0.f};
    for (int e = e0; e < e1; e += 32) {
        int i0 = e + slot, i1 = i0 + 8, i2 = i0 + 16, i3 = i0 + 24;
        unsigned int a0 = csr_src[i0];
        unsigned int a1 = csr_src[i1];
        unsigned int a2 = csr_src[i2];
        unsigned int a3 = csr_src[i3];
        a0 = (i0 < e1) ? a0 : ZROW;
        a1 = (i1 < e1) ? a1 : ZROW;
        a2 = (i2 < e1) ? a2 : ZROW;
        a3 = (i3 < e1) ? a3 : ZROW;
        uint4 v0 = t4[(size_t)a0 * 8 + ch8];
        uint4 v1 = t4[(size_t)a1 * 8 + ch8];
        uint4 v2 = t4[(size_t)a2 * 8 + ch8];
        uint4 v3 = t4[(size_t)a3 * 8 + ch8];
        ACC8(v0);
        ACC8(v1);
        ACC8(v2);
        ACC8(v3);
    }
    float s[8] = {s01.x, s01.y, s23.x, s23.y, s45.x, s45.y, s67.x, s67.y};
#pragma unroll
    for (int d = 8; d <= 32; d <<= 1) {
#pragma unroll
        for (int j = 0; j < 8; ++j) s[j] += __shfl_xor(s[j], d, 64);
    }
    // h1 channels [8*ch8, 8*ch8+8) in f32 (replicated across slot groups)
    const float4 b0 = ((const float4*)b)[ch8 * 2];
    const float4 b1v = ((const float4*)b)[ch8 * 2 + 1];
    float r[8];
    r[0] = fmaxf(s[0] + b0.x, 0.f);
    r[1] = fmaxf(s[1] + b0.y, 0.f);
    r[2] = fmaxf(s[2] + b0.z, 0.f);
    r[3] = fmaxf(s[3] + b0.w, 0.f);
    r[4] = fmaxf(s[4] + b1v.x, 0.f);
    r[5] = fmaxf(s[5] + b1v.y, 0.f);
    r[6] = fmaxf(s[6] + b1v.z, 0.f);
    r[7] = fmaxf(s[7] + b1v.w, 0.f);
    // fused layer-2 linear: outputs n in [8*slot, 8*slot+8)
    float p[8];
#pragma unroll
    for (int n = 0; n < 8; ++n) {
        const float* wrow = W2 + (slot * 8 + n) * 64 + ch8 * 8;
        const float4 wa = *(const float4*)wrow;
        const float4 wb = *(const float4*)(wrow + 4);
        float t = r[0] * wa.x + r[1] * wa.y + r[2] * wa.z + r[3] * wa.w
                + r[4] * wb.x + r[5] * wb.y + r[6] * wb.z + r[7] * wb.w;
        t += __shfl_xor(t, 1, 64);    // sum over ch8 lanes
        t += __shfl_xor(t, 2, 64);
        t += __shfl_xor(t, 4, 64);
        p[n] = t;
    }
    if (ch8 == 0) {
        uint4 w;
        w.x = pk_bf16(p[0], p[1]);
        w.y = pk_bf16(p[2], p[3]);
        w.z = pk_bf16(p[4], p[5]);
        w.w = pk_bf16(p[6], p[7]);
        ((uint4*)(t2 + (size_t)node * 32))[slot] = w;
    }
}

// Layer-2 gather + bias b2 + relu + FUSED W3 projection -> bf16 t3 (16 B rows).
// Block 0 zeroes t3 row ZROW for gather7's OOB redirect.
__global__ __launch_bounds__(256) void gather64b_w3(const int* __restrict__ off,
                                                    const unsigned int* __restrict__ csr_src,
                                                    const unsigned int* __restrict__ tb,
                                                    const float* __restrict__ b,
                                                    const float* __restrict__ W3,
                                                    unsigned int* __restrict__ t3) {
    if (blockIdx.x == 0 && threadIdx.x < 4)
        t3[(size_t)ZROW * 4 + threadIdx.x] = 0u;
    int node = blockIdx.x * 4 + (threadIdx.x >> 6);
    if (node >= N_NODES) return;
    const int lane = threadIdx.x & 63;
    const int slot = lane >> 3;
    const int ch8  = lane & 7;
    int e0 = off[node], e1 = off[node + 1];
    const uint4* t4 = (const uint4*)tb;
    f32x2 s01 = {0.f, 0.f}, s23 = {0.f, 0.f}, s45 = {0.f, 0.f}, s67 = {0.f, 0.f};
    for (int e = e0; e < e1; e += 32) {
        int i0 = e + slot, i1 = i0 + 8, i2 = i0 + 16, i3 = i0 + 24;
        unsigned int a0 = csr_src[i0];
        unsigned int a1 = csr_src[i1];
        unsigned int a2 = csr_src[i2];
        unsigned int a3 = csr_src[i3];
        a0 = (i0 < e1) ? a0 : ZROW;
        a1 = (i1 < e1) ? a1 : ZROW;
        a2 = (i2 < e1) ? a2 : ZROW;
        a3 = (i3 < e1) ? a3 : ZROW;
        uint4 v0 = t4[(size_t)a0 * 8 + ch8];
        uint4 v1 = t4[(size_t)a1 * 8 + ch8];
        uint4 v2 = t4[(size_t)a2 * 8 + ch8];
        uint4 v3 = t4[(size_t)a3 * 8 + ch8];
        ACC8(v0);
        ACC8(v1);
        ACC8(v2);
        ACC8(v3);
    }
    float s[8] = {s01.x, s01.y, s23.x, s23.y, s45.x, s45.y, s67.x, s67.y};
#pragma unroll
    for (int d = 8; d <= 32; d <<= 1) {
#pragma unroll
        for (int j = 0; j < 8; ++j) s[j] += __shfl_xor(s[j], d, 64);
    }
    const float4 b0 = ((const float4*)b)[ch8 * 2];
    const float4 b1v = ((const float4*)b)[ch8 * 2 + 1];
    float r[8];
    r[0] = fmaxf(s[0] + b0.x, 0.f);
    r[1] = fmaxf(s[1] + b0.y, 0.f);
    r[2] = fmaxf(s[2] + b0.z, 0.f);
    r[3] = fmaxf(s[3] + b0.w, 0.f);
    r[4] = fmaxf(s[4] + b1v.x, 0.f);
    r[5] = fmaxf(s[5] + b1v.y, 0.f);
    r[6] = fmaxf(s[6] + b1v.z, 0.f);
    r[7] = fmaxf(s[7] + b1v.w, 0.f);
    float p[7];
#pragma unroll
    for (int j = 0; j < 7; ++j) {
        const float4 wa = *(const float4*)(W3 + j * 64 + ch8 * 8);
        const float4 wb = *(const float4*)(W3 + j * 64 + ch8 * 8 + 4);
        float t = r[0] * wa.x + r[1] * wa.y + r[2] * wa.z + r[3] * wa.w
                + r[4] * wb.x + r[5] * wb.y + r[6] * wb.z + r[7] * wb.w;
        t += __shfl_xor(t, 1, 64);
        t += __shfl_xor(t, 2, 64);
        t += __shfl_xor(t, 4, 64);
        p[j] = t;
    }
    if (lane == 0) {
        uint4 w;
        w.x = pk_bf16(p[0], p[1]);
        w.y = pk_bf16(p[2], p[3]);
        w.z = pk_bf16(p[4], p[5]);
        w.w = pk_bf16(p[6], 0.f);
        *(uint4*)(t3 + (size_t)node * 4) = w;
    }
}

// 7-ch gather + bias + log_softmax (bf16 t3, 16 B rows). Round-3 proven form.
__global__ __launch_bounds__(256) void gather7_lsm(const int* __restrict__ off,
                                                   const unsigned int* __restrict__ csr_src,
                                                   const unsigned int* __restrict__ t3,
                                                   const float* __restrict__ b,
                                                   float* __restrict__ out) {
    int node = blockIdx.x * 4 + (threadIdx.x >> 6);
    if (node >= N_NODES) return;
    const int lane = threadIdx.x & 63;
    const int slot = lane >> 1;
    const int h    = lane & 1;
    int e0 = off[node], e1 = off[node + 1];
    const uint2* t2 = (const uint2*)t3;
    float sx = 0.f, sy = 0.f, sz = 0.f, sw = 0.f;
    for (int e = e0; e < e1; e += 64) {
        int i0 = e + slot;
        int i1 = e + 32 + slot;
        unsigned int a0 = csr_src[i0];
        unsigned int a1 = csr_src[i1];
        a0 = (i0 < e1) ? a0 : ZROW;
        a1 = (i1 < e1) ? a1 : ZROW;
        uint2 v0 = t2[(size_t)a0 * 2 + h];
        uint2 v1 = t2[(size_t)a1 * 2 + h];
        sx += __uint_as_float(v0.x << 16);
        sy += __uint_as_float(v0.x & 0xFFFF0000u);
        sz += __uint_as_float(v0.y << 16);
        sw += __uint_as_float(v0.y & 0xFFFF0000u);
        sx += __uint_as_float(v1.x << 16);
        sy += __uint_as_float(v1.x & 0xFFFF0000u);
        sz += __uint_as_float(v1.y << 16);
        sw += __uint_as_float(v1.y & 0xFFFF0000u);
    }
#pragma unroll
    for (int d = 2; d <= 32; d <<= 1) {
        sx += __shfl_xor(sx, d, 64); sy += __shfl_xor(sy, d, 64);
        sz += __shfl_xor(sz, d, 64); sw += __shfl_xor(sw, d, 64);
    }
    float z0 = sx + b[h * 4 + 0];
    float z1 = sy + b[h * 4 + 1];
    float z2 = sz + b[h * 4 + 2];
    float z3 = (h == 0) ? (sw + b[3]) : -1e30f;
    float m = fmaxf(fmaxf(z0, z1), fmaxf(z2, z3));
    m = fmaxf(m, __shfl_xor(m, 1, 64));
    float ex = __expf(z0 - m) + __expf(z1 - m) + __expf(z2 - m) + __expf(z3 - m);
    ex += __shfl_xor(ex, 1, 64);
    float l = m + __logf(ex);
    if (lane < 2) {
        float* o = out + (size_t)node * 7 + h * 4;
        o[0] = z0 - l; o[1] = z1 - l; o[2] = z2 - l;
        if (h == 0) o[3] = z3 - l;
    }
}

extern "C" void kernel_launch(void* const* d_in, const int* in_sizes, int n_in,
                              void* d_out, int out_size, void* d_ws, size_t ws_size,
                              hipStream_t stream) {
    const float* x  = (const float*)d_in[0];
    const int*   ei = (const int*)d_in[1];
    const float* W1 = (const float*)d_in[2];
    const float* b1 = (const float*)d_in[3];
    const float* W2 = (const float*)d_in[4];
    const float* b2 = (const float*)d_in[5];
    const float* W3 = (const float*)d_in[6];
    const float* b3 = (const float*)d_in[7];
    float* out = (float*)d_out;

    const int* src = ei;
    const int* dst = ei + N_EDGES;

    // workspace:
    //   A (12.8 MB): buckets (8 MB, dead after build_csr) -> bf16 t2 table
    //                (6.4 MB + ZROW row)
    //   B (12.8 MB): bf16 t table (6.4 MB + ZROW)  then t3 (0.8 MB + ZROW)
    //   then csr (6.4 MB; over-read lands in off), off, gcursor, Wb1
    float* A = (float*)d_ws;
    float* B = A + (size_t)N_NODES * C;
    unsigned int* csr = (unsigned int*)(B + (size_t)N_NODES * C);
    int* off     = (int*)(csr + N_EDGES);          // 50001
    int* gcursor = off + N_NODES + 8;              // 196
    unsigned int* Wb1 = (unsigned int*)(gcursor + 256);   // 2048 u32
    unsigned int* buckets = (unsigned int*)A;
    unsigned int* T2 = (unsigned int*)A;           // t2 (over dead buckets)
    unsigned int* Tt = (unsigned int*)B;           // layer-1 t (+ZROW)
    unsigned int* T3 = Tt + (size_t)(N_NODES + 1) * 32;   // after t in B

    const int mfmagrid = (N_NODES + 63) / 64;      // 782 blocks x 4 waves
    const int ngrid    = (N_NODES + 3) / 4;        // 12500

    // ---- prep: pack W1 + zero gcursor
    prep<<<9, 256, 0, stream>>>(W1, Wb1, gcursor);

    // ---- fused: edge binning + layer-1 linear (independent work, 1 dispatch)
    bin_lin1<<<BINBLKS + mfmagrid, 256, 0, stream>>>(src, dst, buckets, gcursor,
                                                     x, Wb1, Tt);

    // ---- CSR phase 2
    build_csr<<<NB, 256, 0, stream>>>(buckets, gcursor, csr, off);

    // ---- layer-1 gather + fused layer-2 linear (h1 never hits memory)
    gather64_lin2<<<ngrid, 256, 0, stream>>>(off, csr, Tt, b1, W2, T2);

    // ---- layer-2 gather + fused W3 projection (h2 never hits memory)
    gather64b_w3<<<ngrid, 256, 0, stream>>>(off, csr, T2, b2, W3, T3);

    // ---- layer-3 aggregation + log_softmax
    gather7_lsm<<<ngrid, 256, 0, stream>>>(off, csr, T3, b3, out);
}